// Round 10
// baseline (341.532 us; speedup 1.0000x reference)
//
#include <hip/hip_runtime.h>
#include <hip/hip_bf16.h>

#define DEV __device__ __forceinline__

typedef __attribute__((ext_vector_type(8))) short bf16x8;   // 8 bf16 = 4 VGPR (MFMA A/B frag)
typedef __attribute__((ext_vector_type(4))) short bf16x4;   // 4 bf16 = 2 VGPR (ds_read_b64)
typedef __attribute__((ext_vector_type(4))) float f32x4;    // MFMA C/D frag

DEV unsigned short f2bf(float v) {
    union { __hip_bfloat16 b; unsigned short u; } c;
    c.b = __float2bfloat16(v);
    return c.u;
}

// ---------------------------------------------------------------------------
// Workspace layout (bytes).
// ---------------------------------------------------------------------------
#define OFF_X1P   0
#define OFF_X2P   99123200
#define OFF_X3P   126208000
#define OFF_W1T   140953600
#define OFF_W2T   140964096
#define OFF_W3T   141056256
#define OFF_W4T   141240576
#define OFF_F4    0
#define OFF_G     20480000
#define OFF_PROTO 21299200

// ---------------------------------------------------------------------------
// border-ring zero (all three padded buffers in ONE launch, grid 1200)
// ---------------------------------------------------------------------------
template<int HP, int WP, int C>
DEV void ring_zero(short* __restrict__ Xp, int img)
{
    constexpr int RING = 2 * WP + 2 * (HP - 2);
    constexpr int U = C / 8;
    short* base = Xp + (size_t)img * (HP * WP * C);
    uint4 z; z.x = z.y = z.z = z.w = 0;
    for (int i = threadIdx.x; i < RING * U; i += 256) {
        int r = i / U, u = i % U;
        int y, x;
        if (r < WP)            { y = 0;      x = r; }
        else if (r < 2 * WP)   { y = HP - 1; x = r - WP; }
        else { int s = r - 2 * WP; y = 1 + (s >> 1); x = (s & 1) ? (WP - 1) : 0; }
        *(uint4*)(base + ((size_t)(y * WP + x)) * C + u * 8) = z;
    }
}

__global__ __launch_bounds__(256)
void border_zero_all_kernel(short* __restrict__ X1p, short* __restrict__ X2p,
                            short* __restrict__ X3p)
{
    int b = blockIdx.x;
    if (b < 400)      ring_zero<44, 44, 64>(X1p, b);
    else if (b < 800) ring_zero<23, 23, 64>(X2p, b - 400);
    else              ring_zero<12, 12, 128>(X3p, b - 800);
}

// ---------------------------------------------------------------------------
// weight transforms (ALL in one launch): OIHW f32 -> bf16 MFMA fragment layout
// conv1: k = tap*4 + cin (cin padded 3->4), [64 cout][80] (k 36..79 zero)
// conv2/3/4: k = tap*CIN + cin, chunks of 32: [KC][COUT][40]
// ---------------------------------------------------------------------------
template<int COUT, int CIN>
DEV void wt_tap_elem(const float* __restrict__ w, short* __restrict__ dst, int t)
{
    int cout = t / (CIN * 9), k = t % (CIN * 9);
    int tap = k / CIN, cin = k % CIN;
    float v = w[((size_t)cout * CIN + cin) * 9 + tap];
    dst[((size_t)(k >> 5) * COUT + cout) * 40 + (k & 31)] = (short)f2bf(v);
}

__global__ __launch_bounds__(256)
void wt_all_kernel(const float* __restrict__ w1, const float* __restrict__ w2,
                   const float* __restrict__ w3, const float* __restrict__ w4,
                   short* __restrict__ W1t, short* __restrict__ W2t,
                   short* __restrict__ W3t, short* __restrict__ W4t)
{
    int t = blockIdx.x * 256 + threadIdx.x;
    if (t < 5120) {
        int cout = t / 80, kk = t % 80;
        int tap = kk >> 2, cin = kk & 3;
        float v = (tap < 9 && cin < 3) ? w1[(cout * 3 + cin) * 9 + tap] : 0.f;
        W1t[cout * 80 + kk] = (short)f2bf(v);
        return;
    }
    t -= 5120;
    if (t < 36864) { wt_tap_elem<64, 64>(w2, W2t, t); return; }
    t -= 36864;
    if (t < 73728) { wt_tap_elem<128, 64>(w3, W3t, t); return; }
    t -= 73728;
    if (t < 589824) wt_tap_elem<512, 128>(w4, W4t, t);
}

// ---------------------------------------------------------------------------
// conv1: pixels = MFMA A-operand (M dim), weights = B (N dim). Pool partners
// land in acc regs 0..3 of one lane -> pooling = 3 v_max_f32, 1 store/lane.
// ---------------------------------------------------------------------------
__global__ __launch_bounds__(256, 2)
void conv1_mfma_kernel(const float* __restrict__ xtrain, const float* __restrict__ xtest,
                       const short* __restrict__ W1t, const float* __restrict__ bias,
                       short* __restrict__ X1p)
{
    constexpr int RSTR = 352;            // row stride (86*4 pad to 352)
    __shared__ short sr[8 * RSTR];       // 5632 B
    __shared__ float sb[64];

    const int tid = threadIdx.x;
    const int img = blockIdx.x / 14, blkrow = blockIdx.x % 14;
    const int yp0 = blkrow * 3;
    const float* src = (img < 100) ? xtrain + (size_t)img * (3 * 84 * 84)
                                   : xtest  + (size_t)(img - 100) * (3 * 84 * 84);
    const int wv = tid >> 6, lane = tid & 63, quad = lane >> 4, ln = lane & 15;

    for (int i = tid; i < 8 * 86; i += 256) {
        int r = i / 86, c = i % 86;
        int gy = 2 * yp0 - 1 + r, gx = c - 1;
        bf16x4 v = (bf16x4)0;
        if (gy >= 0 && gy < 84 && gx >= 0 && gx < 84) {
            int o = gy * 84 + gx;
            v[0] = (short)f2bf(src[o]);
            v[1] = (short)f2bf(src[7056 + o]);
            v[2] = (short)f2bf(src[14112 + o]);
        }
        *(bf16x4*)(&sr[r * RSTR + c * 4]) = v;
    }
    if (tid < 64) sb[tid] = bias[tid];

    const int t0 = 2 * quad, t1 = 2 * quad + 1;
    const int off0 = (t0 / 3) * RSTR + (t0 % 3) * 4;
    const int off1 = (t1 / 3) * RSTR + (t1 % 3) * 4;
    const int off2 = 2 * RSTR + 2 * 4;   // tap 8 = (2,2)

    bf16x8 af0[4], af1[4];
    #pragma unroll
    for (int mi = 0; mi < 4; ++mi) {
        af0[mi] = *(const bf16x8*)(W1t + (mi * 16 + ln) * 80 + quad * 8);
        af1[mi] = *(const bf16x8*)(W1t + (mi * 16 + ln) * 80 + 32 + quad * 8);
    }

    f32x4 acc[4][8];
    #pragma unroll
    for (int mi = 0; mi < 4; ++mi)
        #pragma unroll
        for (int ni = 0; ni < 8; ++ni) acc[mi][ni] = (f32x4)0.f;

    __syncthreads();

    #pragma unroll
    for (int ni = 0; ni < 8; ++ni) {
        int q = wv * 128 + ni * 16 + ln;
        int qc = (q < 504) ? q : 503;
        int ypl = qc / 168, rem = qc % 168;
        int x = rem >> 1, dy = rem & 1;
        int base = (2 * ypl + dy) * RSTR + x * 4;

        bf16x4 lo0 = *(const bf16x4*)(&sr[base + off0]);
        bf16x4 hi0 = *(const bf16x4*)(&sr[base + off1]);
        bf16x8 b0;
        #pragma unroll
        for (int j = 0; j < 4; ++j) { b0[j] = lo0[j]; b0[4 + j] = hi0[j]; }
        bf16x4 lo1 = *(const bf16x4*)(&sr[base + off2]);
        bf16x8 b1;
        #pragma unroll
        for (int j = 0; j < 4; ++j) { b1[j] = lo1[j]; b1[4 + j] = lo1[j]; }

        #pragma unroll
        for (int mi = 0; mi < 4; ++mi) {
            acc[mi][ni] = __builtin_amdgcn_mfma_f32_16x16x32_bf16(b0, af0[mi], acc[mi][ni], 0, 0, 0);
            acc[mi][ni] = __builtin_amdgcn_mfma_f32_16x16x32_bf16(b1, af1[mi], acc[mi][ni], 0, 0, 0);
        }
    }

    #pragma unroll
    for (int ni = 0; ni < 8; ++ni) {
        int g = wv * 32 + ni * 4 + quad;
        bool ok = (g < 126);
        int ypl = g / 42, xg = g % 42;
        #pragma unroll
        for (int mi = 0; mi < 4; ++mi) {
            f32x4 a = acc[mi][ni];
            float m = fmaxf(fmaxf(a[0], a[1]), fmaxf(a[2], a[3]));
            if (ok) {
                int cout = mi * 16 + ln;
                unsigned short h = f2bf(fmaxf(m + sb[cout], 0.f));
                int py = yp0 + ypl;
                size_t o = (((size_t)img * 44 + py + 1) * 44 + xg + 1) * 64 + cout;
                X1p[o] = (short)h;
            }
        }
    }
}

// ---------------------------------------------------------------------------
// conv2/conv3: MFMA implicit GEMM, pixels = A (M), weights = B (N).
// Depth-2 global af prefetch (mod-3 buffers), depth-1 LDS bf prefetch (mod-2),
// K-loop unrolled x6, NO barriers in the K-loop, reg-pool epilogue.
// KC must be divisible by 6 (18 / 18 / 36 all are).
// ---------------------------------------------------------------------------
template<int CIN, int COUT, int NWM, int NWN, int MT, int NT, int YPB,
         int WOUT, int HPIN, int WPIN, int HPO, int WPO, int RBI>
__global__ __launch_bounds__(256, 2)
void conv_mfma_kernel(const short* __restrict__ Xp, const short* __restrict__ Wt,
                      const float* __restrict__ bias, short* __restrict__ Yp)
{
    constexpr int ROWS = 2 * YPB + 2, CSTR = CIN + 8;
    constexpr int KC = CIN * 9 / 32, CPT = CIN / 32;
    constexpr int WPAIR = (2 * WOUT + 3) / 4 * 4;
    constexpr int NSLOT = YPB * WPAIR, POOLW = WOUT / 2;
    constexpr int GPR = WPAIR / 4;
    static_assert(KC % 6 == 0, "KC must divide 6");
    __shared__ short sx[ROWS * WPIN * CSTR];
    __shared__ float sb[COUT];

    const int tid = threadIdx.x;
    const int img = blockIdx.x / RBI, blkrow = blockIdx.x % RBI;
    const int yp0 = blkrow * YPB;
    const int wv = tid >> 6, lane = tid & 63, quad = lane >> 4, ln = lane & 15;
    const int msup = (NWM == 1) ? 0 : (wv >> 1);
    const int nsup = (NWM == 1) ? wv : (wv & 1);

    const short* xsrc = Xp + ((size_t)img * HPIN + 2 * yp0) * (WPIN * CIN);
    for (int i = tid; i < ROWS * WPIN * (CIN / 8); i += 256) {
        int g = i % (CIN / 8), pc = i / (CIN / 8);
        uint4 v = *(const uint4*)(xsrc + (size_t)pc * CIN + g * 8);
        *(uint4*)(&sx[pc * CSTR + g * 8]) = v;
    }
    for (int i = tid; i < COUT; i += 256) sb[i] = bias[i];

    int pbase[NT];
    #pragma unroll
    for (int ni = 0; ni < NT; ++ni) {
        int q = nsup * (NT * 16) + ni * 16 + ln;
        int qc = (q < NSLOT) ? q : (NSLOT - 1);
        int ypl = qc / WPAIR, rem = qc % WPAIR;
        int x = rem >> 1; if (x > WOUT - 1) x = WOUT - 1;
        int dy = rem & 1;
        pbase[ni] = (((2 * ypl + dy) * WPIN + x) * CSTR + quad * 8) * 2;
    }

    f32x4 acc[MT][NT];
    #pragma unroll
    for (int mi = 0; mi < MT; ++mi)
        #pragma unroll
        for (int ni = 0; ni < NT; ++ni) acc[mi][ni] = (f32x4)0.f;

    auto loadAF = [&](bf16x8* dst, int kc) {
        #pragma unroll
        for (int mi = 0; mi < MT; ++mi)
            dst[mi] = *(const bf16x8*)(Wt + ((size_t)kc * COUT + msup * 64 + mi * 16 + ln) * 40 + quad * 8);
    };
    auto loadBF = [&](bf16x8* dst, int kc) {
        const int tap = kc / CPT, cb = (kc % CPT) * 32;
        const int ky = tap / 3, kx = tap % 3;
        const int koff = ((ky * WPIN + kx) * CSTR + cb) * 2;
        #pragma unroll
        for (int ni = 0; ni < NT; ++ni)
            dst[ni] = *(const bf16x8*)((const char*)sx + pbase[ni] + koff);
    };

    __syncthreads();   // sx/sb ready — the ONLY barrier

    bf16x8 af[3][MT], bf[2][NT];
    loadAF(af[0], 0); loadAF(af[1], 1); loadBF(bf[0], 0);
    for (int kc = 0; kc < KC; kc += 6) {
        #pragma unroll
        for (int j = 0; j < 6; ++j) {
            int ka = kc + j + 2; if (ka > KC - 1) ka = KC - 1;
            int kb = kc + j + 1; if (kb > KC - 1) kb = KC - 1;
            loadAF(af[(j + 2) % 3], ka);
            loadBF(bf[(j + 1) & 1], kb);
            #pragma unroll
            for (int mi = 0; mi < MT; ++mi)
                #pragma unroll
                for (int ni = 0; ni < NT; ++ni)
                    acc[mi][ni] = __builtin_amdgcn_mfma_f32_16x16x32_bf16(
                        bf[j & 1][ni], af[j % 3][mi], acc[mi][ni], 0, 0, 0);
        }
    }

    #pragma unroll
    for (int ni = 0; ni < NT; ++ni) {
        int g = nsup * (NT * 4) + ni * 4 + quad;
        int ypl = g / GPR, xg = g % GPR;
        bool ok = (g < NSLOT / 4) && (xg < POOLW);
        #pragma unroll
        for (int mi = 0; mi < MT; ++mi) {
            f32x4 a = acc[mi][ni];
            float m = fmaxf(fmaxf(a[0], a[1]), fmaxf(a[2], a[3]));
            if (ok) {
                int cout = msup * 64 + mi * 16 + ln;
                unsigned short h = f2bf(fmaxf(m + sb[cout], 0.f));
                int py = yp0 + ypl;
                Yp[(((size_t)img * HPO + py + 1) * WPO + xg + 1) * COUT + cout] = (short)h;
            }
        }
    }
}

// ---------------------------------------------------------------------------
// conv4: image in LDS (CSTR=136), depth-2 af prefetch, depth-1 bf, unroll x6,
// no K-loop barriers, reg-pool epilogue -> f4 NHWC f32 (400,25,512).
// ---------------------------------------------------------------------------
__global__ __launch_bounds__(256, 2)
void conv4_mfma_kernel(const short* __restrict__ X3p, const short* __restrict__ W4t,
                       const float* __restrict__ bias, float* __restrict__ f4)
{
    constexpr int CSTR = 136;
    __shared__ short sx[144 * CSTR];     // 39,168 B
    __shared__ float sb[128];

    const int tid = threadIdx.x;
    const int img = blockIdx.x >> 2, mb = blockIdx.x & 3;
    const int wv = tid >> 6, lane = tid & 63, quad = lane >> 4, ln = lane & 15;
    const int msup = wv >> 1, nsup = wv & 1;

    const short* xsrc = X3p + (size_t)img * (144 * 128);
    for (int i = tid; i < 144 * 16; i += 256) {
        int pc = i >> 4, g = i & 15;
        uint4 v = *(const uint4*)(xsrc + pc * 128 + g * 8);
        *(uint4*)(&sx[pc * CSTR + g * 8]) = v;
    }
    for (int i = tid; i < 128; i += 256) sb[i] = bias[mb * 128 + i];

    int pbase[4];
    #pragma unroll
    for (int ni = 0; ni < 4; ++ni) {
        int q = nsup * 64 + ni * 16 + ln;
        int pc = (q < 100) ? q : 99;
        int yp = pc / 20, rem = pc % 20;
        int y = 2 * yp + (rem & 1), x = rem >> 1;
        pbase[ni] = ((y * 12 + x) * CSTR + quad * 8) * 2;
    }

    f32x4 acc[4][4];
    #pragma unroll
    for (int mi = 0; mi < 4; ++mi)
        #pragma unroll
        for (int ni = 0; ni < 4; ++ni) acc[mi][ni] = (f32x4)0.f;

    auto loadAF = [&](bf16x8* dst, int kc) {
        #pragma unroll
        for (int mi = 0; mi < 4; ++mi)
            dst[mi] = *(const bf16x8*)(W4t + ((size_t)kc * 512 + mb * 128 + msup * 64 + mi * 16 + ln) * 40 + quad * 8);
    };
    auto loadBF = [&](bf16x8* dst, int kc) {
        const int tap = kc >> 2, cb = (kc & 3) * 32;
        const int ky = tap / 3, kx = tap % 3;
        const int koff = ((ky * 12 + kx) * CSTR + cb) * 2;
        #pragma unroll
        for (int ni = 0; ni < 4; ++ni)
            dst[ni] = *(const bf16x8*)((const char*)sx + pbase[ni] + koff);
    };

    __syncthreads();   // sx/sb ready — the ONLY barrier

    bf16x8 af[3][4], bf[2][4];
    loadAF(af[0], 0); loadAF(af[1], 1); loadBF(bf[0], 0);
    for (int kc = 0; kc < 36; kc += 6) {
        #pragma unroll
        for (int j = 0; j < 6; ++j) {
            int ka = kc + j + 2; if (ka > 35) ka = 35;
            int kb = kc + j + 1; if (kb > 35) kb = 35;
            loadAF(af[(j + 2) % 3], ka);
            loadBF(bf[(j + 1) & 1], kb);
            #pragma unroll
            for (int mi = 0; mi < 4; ++mi)
                #pragma unroll
                for (int ni = 0; ni < 4; ++ni)
                    acc[mi][ni] = __builtin_amdgcn_mfma_f32_16x16x32_bf16(
                        bf[j & 1][ni], af[j % 3][mi], acc[mi][ni], 0, 0, 0);
        }
    }

    #pragma unroll
    for (int ni = 0; ni < 4; ++ni) {
        int g = nsup * 16 + ni * 4 + quad;
        bool ok = (g < 25);
        #pragma unroll
        for (int mi = 0; mi < 4; ++mi) {
            f32x4 a = acc[mi][ni];
            float m = fmaxf(fmaxf(a[0], a[1]), fmaxf(a[2], a[3]));
            if (ok) {
                int cl = msup * 64 + mi * 16 + ln;
                f4[((size_t)img * 25 + g) * 512 + mb * 128 + cl] = fmaxf(m + sb[cl], 0.f);
            }
        }
    }
}

// ---------------------------------------------------------------------------
// heads (f4 NHWC f32 (400,25,512) -> g, proto, predict, cls)
// ---------------------------------------------------------------------------
__global__ __launch_bounds__(256)
void gap_kernel(const float* __restrict__ f4, float* __restrict__ g)
{
    const int img = blockIdx.x;
    for (int c = threadIdx.x; c < 512; c += 256) {
        float s = 0.f;
        #pragma unroll
        for (int p = 0; p < 25; ++p)
            s += f4[((size_t)img * 25 + p) * 512 + c];
        g[(size_t)img * 512 + c] = s * (1.f / 25.f);
    }
}

__global__ __launch_bounds__(256)
void proto_kernel(const float* __restrict__ g, const float* __restrict__ ytrain,
                  float* __restrict__ proto)
{
    const int b = blockIdx.x / 5, k = blockIdx.x % 5;
    __shared__ float sp[512];
    __shared__ float red[256];

    float yv[25];
    float cnt = 0.f;
    for (int n = 0; n < 25; ++n) {
        yv[n] = ytrain[(size_t)(b * 25 + n) * 5 + k];
        cnt += yv[n];
    }
    const float icnt = 1.f / cnt;

    for (int c = threadIdx.x; c < 512; c += 256) {
        float s = 0.f;
        for (int n = 0; n < 25; ++n)
            s += yv[n] * g[((size_t)(b * 25 + n)) * 512 + c];
        sp[c] = s * icnt;
    }
    __syncthreads();

    float ss = 0.f;
    for (int c = threadIdx.x; c < 512; c += 256) ss += sp[c] * sp[c];
    red[threadIdx.x] = ss;
    __syncthreads();
    for (int s = 128; s > 0; s >>= 1) {
        if (threadIdx.x < s) red[threadIdx.x] += red[threadIdx.x + s];
        __syncthreads();
    }
    const float inv = 1.f / fmaxf(sqrtf(red[0]), 1e-12f);
    for (int c = threadIdx.x; c < 512; c += 256)
        proto[((size_t)(b * 5 + k)) * 512 + c] = sp[c] * inv;
}

__global__ __launch_bounds__(64)
void predict_kernel(const float* __restrict__ g, const float* __restrict__ wc,
                    const float* __restrict__ bc, float* __restrict__ out)
{
    const int q = blockIdx.x;
    __shared__ float fq[512];
    const float* gq = g + (size_t)(100 + q) * 512;
    float ss = 0.f;
    for (int c = threadIdx.x; c < 512; c += 64) {
        const float v = gq[c];
        fq[c] = v;
        ss += v * v;
    }
    #pragma unroll
    for (int o = 32; o > 0; o >>= 1) ss += __shfl_down(ss, o);
    const float inv = 1.f / fmaxf(sqrtf(__shfl(ss, 0)), 1e-12f);
    __syncthreads();

    const int m = threadIdx.x;
    float s = bc[m];
    for (int c = 0; c < 512; ++c)
        s = fmaf(fq[c] * inv, wc[m * 512 + c], s);
    out[q * 64 + m] = s;
}

__global__ __launch_bounds__(256)
void cls_kernel(const float* __restrict__ f4, const float* __restrict__ proto,
                float* __restrict__ outc)
{
    __shared__ float sf[25 * 516];      // +4 pad kills 512-stride bank conflicts
    __shared__ float spr[5 * 516];
    const int q = blockIdx.x, b = q / 75;
    const float* f = f4 + (size_t)(100 + q) * (25 * 512);
    for (int i = threadIdx.x; i < 3200; i += 256) {
        int row = i >> 7, col = i & 127;
        *(float4*)(&sf[row * 516 + col * 4]) = *(const float4*)(f + row * 512 + col * 4);
    }
    const float* pb = proto + (size_t)b * 5 * 512;
    for (int i = threadIdx.x; i < 640; i += 256) {
        int row = i >> 7, col = i & 127;
        *(float4*)(&spr[row * 516 + col * 4]) = *(const float4*)(pb + row * 512 + col * 4);
    }
    __syncthreads();

    for (int it = threadIdx.x; it < 125; it += 256) {
        int i = it / 25, p = it % 25;
        const float* fp = &sf[p * 516];
        const float* pr = &spr[i * 516];
        float ss = 0.f, dot = 0.f;
        for (int c = 0; c < 512; c += 4) {
            float4 v = *(const float4*)(fp + c);
            float4 w = *(const float4*)(pr + c);
            ss  += v.x * v.x + v.y * v.y + v.z * v.z + v.w * v.w;
            dot += v.x * w.x + v.y * w.y + v.z * w.z + v.w * w.w;
        }
        outc[(size_t)q * 125 + it] = dot / fmaxf(sqrtf(ss), 1e-12f);
    }
}

// ---------------------------------------------------------------------------
extern "C" void kernel_launch(void* const* d_in, const int* in_sizes, int n_in,
                              void* d_out, int out_size, void* d_ws, size_t ws_size,
                              hipStream_t stream)
{
    (void)in_sizes; (void)n_in; (void)out_size; (void)ws_size;
    const float* xtrain = (const float*)d_in[0];
    const float* xtest  = (const float*)d_in[1];
    const float* ytrain = (const float*)d_in[2];
    const float* w1 = (const float*)d_in[4];
    const float* b1 = (const float*)d_in[5];
    const float* w2 = (const float*)d_in[6];
    const float* b2 = (const float*)d_in[7];
    const float* w3 = (const float*)d_in[8];
    const float* b3 = (const float*)d_in[9];
    const float* w4 = (const float*)d_in[10];
    const float* b4 = (const float*)d_in[11];
    const float* wc = (const float*)d_in[12];
    const float* bc = (const float*)d_in[13];

    char* ws = (char*)d_ws;
    short* X1p = (short*)(ws + OFF_X1P);
    short* X2p = (short*)(ws + OFF_X2P);
    short* X3p = (short*)(ws + OFF_X3P);
    short* W1t = (short*)(ws + OFF_W1T);
    short* W2t = (short*)(ws + OFF_W2T);
    short* W3t = (short*)(ws + OFF_W3T);
    short* W4t = (short*)(ws + OFF_W4T);
    float* f4    = (float*)(ws + OFF_F4);
    float* g     = (float*)(ws + OFF_G);
    float* proto = (float*)(ws + OFF_PROTO);
    float* out = (float*)d_out;

    // setup: pad rings (1 launch) + weight transforms (1 launch)
    border_zero_all_kernel<<<1200, 256, 0, stream>>>(X1p, X2p, X3p);
    wt_all_kernel<<<2756, 256, 0, stream>>>(w1, w2, w3, w4, W1t, W2t, W3t, W4t);

    // backbone
    conv1_mfma_kernel<<<400 * 14, 256, 0, stream>>>(xtrain, xtest, W1t, b1, X1p);
    //                CIN COUT NWM NWN MT NT YPB WOUT HPIN WPIN HPO WPO RBI
    conv_mfma_kernel< 64,  64,  1,  4, 4, 4,  3,  42,  44,  44, 23, 23,  7>
        <<<400 * 7, 256, 0, stream>>>(X1p, W2t, b2, X2p);
    conv_mfma_kernel< 64, 128,  2,  2, 4, 7,  5,  21,  23,  23, 12, 12,  2>
        <<<400 * 2, 256, 0, stream>>>(X2p, W3t, b3, X3p);
    conv4_mfma_kernel<<<400 * 4, 256, 0, stream>>>(X3p, W4t, b4, f4);

    // heads
    gap_kernel<<<400, 256, 0, stream>>>(f4, g);
    proto_kernel<<<20, 256, 0, stream>>>(g, ytrain, proto);
    predict_kernel<<<300, 64, 0, stream>>>(g, wc, bc, out);
    cls_kernel<<<300, 256, 0, stream>>>(f4, proto, out + 19200);
}

// Round 12
// 315.864 us; speedup vs baseline: 1.0813x; 1.0813x over previous
//
#include <hip/hip_runtime.h>
#include <hip/hip_bf16.h>

#define DEV __device__ __forceinline__

typedef __attribute__((ext_vector_type(8))) short bf16x8;   // 8 bf16 = 4 VGPR (MFMA A/B frag)
typedef __attribute__((ext_vector_type(4))) short bf16x4;   // 4 bf16 = 2 VGPR (ds_read_b64)
typedef __attribute__((ext_vector_type(4))) float f32x4;    // MFMA C/D frag

DEV unsigned short f2bf(float v) {
    union { __hip_bfloat16 b; unsigned short u; } c;
    c.b = __float2bfloat16(v);
    return c.u;
}

// ---------------------------------------------------------------------------
// Workspace layout (bytes). W4t ends at 141,240,576 + 1,474,560 = 142,715,136.
// R11 BUG: wcT was at 141,830,400 — INSIDE W4t — race -> NaN weights. Fixed.
// ---------------------------------------------------------------------------
#define OFF_X1P   0
#define OFF_X2P   99123200
#define OFF_X3P   126208000
#define OFF_W1T   140953600
#define OFF_W2T   140964096
#define OFF_W3T   141056256
#define OFF_W4T   141240576
#define OFF_WCT   142715136     // wc transposed f32 [512][64], AFTER W4t
#define OFF_F4    0
#define OFF_G     20480000
#define OFF_PROTO 21299200

// ---------------------------------------------------------------------------
// border-ring zero (all three padded buffers in ONE launch, grid 1200)
// ---------------------------------------------------------------------------
template<int HP, int WP, int C>
DEV void ring_zero(short* __restrict__ Xp, int img)
{
    constexpr int RING = 2 * WP + 2 * (HP - 2);
    constexpr int U = C / 8;
    short* base = Xp + (size_t)img * (HP * WP * C);
    uint4 z; z.x = z.y = z.z = z.w = 0;
    for (int i = threadIdx.x; i < RING * U; i += 256) {
        int r = i / U, u = i % U;
        int y, x;
        if (r < WP)            { y = 0;      x = r; }
        else if (r < 2 * WP)   { y = HP - 1; x = r - WP; }
        else { int s = r - 2 * WP; y = 1 + (s >> 1); x = (s & 1) ? (WP - 1) : 0; }
        *(uint4*)(base + ((size_t)(y * WP + x)) * C + u * 8) = z;
    }
}

__global__ __launch_bounds__(256)
void border_zero_all_kernel(short* __restrict__ X1p, short* __restrict__ X2p,
                            short* __restrict__ X3p)
{
    int b = blockIdx.x;
    if (b < 400)      ring_zero<44, 44, 64>(X1p, b);
    else if (b < 800) ring_zero<23, 23, 64>(X2p, b - 400);
    else              ring_zero<12, 12, 128>(X3p, b - 800);
}

// ---------------------------------------------------------------------------
// weight transforms (ALL in one launch): OIHW f32 -> bf16 MFMA fragment layout
// conv1: k = tap*4 + cin (cin padded 3->4), [64 cout][80] (k 36..79 zero)
// conv2/3/4: k = tap*CIN + cin, chunks of 32: [KC][COUT][40]
// plus: wc (64,512) f32 -> wcT (512,64) f32 for coalesced predict reads
// ---------------------------------------------------------------------------
template<int COUT, int CIN>
DEV void wt_tap_elem(const float* __restrict__ w, short* __restrict__ dst, int t)
{
    int cout = t / (CIN * 9), k = t % (CIN * 9);
    int tap = k / CIN, cin = k % CIN;
    float v = w[((size_t)cout * CIN + cin) * 9 + tap];
    dst[((size_t)(k >> 5) * COUT + cout) * 40 + (k & 31)] = (short)f2bf(v);
}

__global__ __launch_bounds__(256)
void wt_all_kernel(const float* __restrict__ w1, const float* __restrict__ w2,
                   const float* __restrict__ w3, const float* __restrict__ w4,
                   const float* __restrict__ wc,
                   short* __restrict__ W1t, short* __restrict__ W2t,
                   short* __restrict__ W3t, short* __restrict__ W4t,
                   float* __restrict__ wcT)
{
    int t = blockIdx.x * 256 + threadIdx.x;
    if (t < 5120) {
        int cout = t / 80, kk = t % 80;
        int tap = kk >> 2, cin = kk & 3;
        float v = (tap < 9 && cin < 3) ? w1[(cout * 3 + cin) * 9 + tap] : 0.f;
        W1t[cout * 80 + kk] = (short)f2bf(v);
        return;
    }
    t -= 5120;
    if (t < 36864) { wt_tap_elem<64, 64>(w2, W2t, t); return; }
    t -= 36864;
    if (t < 73728) { wt_tap_elem<128, 64>(w3, W3t, t); return; }
    t -= 73728;
    if (t < 589824) { wt_tap_elem<512, 128>(w4, W4t, t); return; }
    t -= 589824;
    if (t < 32768) {
        int c = t >> 6, m = t & 63;
        wcT[t] = wc[m * 512 + c];
    }
}

// ---------------------------------------------------------------------------
// conv1: pixels = MFMA A-operand (M dim), weights = B (N dim). Pool partners
// land in acc regs 0..3 of one lane -> pooling = 3 v_max_f32, 1 store/lane.
// ---------------------------------------------------------------------------
__global__ __launch_bounds__(256, 2)
void conv1_mfma_kernel(const float* __restrict__ xtrain, const float* __restrict__ xtest,
                       const short* __restrict__ W1t, const float* __restrict__ bias,
                       short* __restrict__ X1p)
{
    constexpr int RSTR = 352;            // row stride (86*4 pad to 352)
    __shared__ short sr[8 * RSTR];       // 5632 B
    __shared__ float sb[64];

    const int tid = threadIdx.x;
    const int img = blockIdx.x / 14, blkrow = blockIdx.x % 14;
    const int yp0 = blkrow * 3;
    const float* src = (img < 100) ? xtrain + (size_t)img * (3 * 84 * 84)
                                   : xtest  + (size_t)(img - 100) * (3 * 84 * 84);
    const int wv = tid >> 6, lane = tid & 63, quad = lane >> 4, ln = lane & 15;

    for (int i = tid; i < 8 * 86; i += 256) {
        int r = i / 86, c = i % 86;
        int gy = 2 * yp0 - 1 + r, gx = c - 1;
        bf16x4 v = (bf16x4)0;
        if (gy >= 0 && gy < 84 && gx >= 0 && gx < 84) {
            int o = gy * 84 + gx;
            v[0] = (short)f2bf(src[o]);
            v[1] = (short)f2bf(src[7056 + o]);
            v[2] = (short)f2bf(src[14112 + o]);
        }
        *(bf16x4*)(&sr[r * RSTR + c * 4]) = v;
    }
    if (tid < 64) sb[tid] = bias[tid];

    const int t0 = 2 * quad, t1 = 2 * quad + 1;
    const int off0 = (t0 / 3) * RSTR + (t0 % 3) * 4;
    const int off1 = (t1 / 3) * RSTR + (t1 % 3) * 4;
    const int off2 = 2 * RSTR + 2 * 4;   // tap 8 = (2,2)

    bf16x8 af0[4], af1[4];
    #pragma unroll
    for (int mi = 0; mi < 4; ++mi) {
        af0[mi] = *(const bf16x8*)(W1t + (mi * 16 + ln) * 80 + quad * 8);
        af1[mi] = *(const bf16x8*)(W1t + (mi * 16 + ln) * 80 + 32 + quad * 8);
    }

    f32x4 acc[4][8];
    #pragma unroll
    for (int mi = 0; mi < 4; ++mi)
        #pragma unroll
        for (int ni = 0; ni < 8; ++ni) acc[mi][ni] = (f32x4)0.f;

    __syncthreads();

    #pragma unroll
    for (int ni = 0; ni < 8; ++ni) {
        int q = wv * 128 + ni * 16 + ln;
        int qc = (q < 504) ? q : 503;
        int ypl = qc / 168, rem = qc % 168;
        int x = rem >> 1, dy = rem & 1;
        int base = (2 * ypl + dy) * RSTR + x * 4;

        bf16x4 lo0 = *(const bf16x4*)(&sr[base + off0]);
        bf16x4 hi0 = *(const bf16x4*)(&sr[base + off1]);
        bf16x8 b0;
        #pragma unroll
        for (int j = 0; j < 4; ++j) { b0[j] = lo0[j]; b0[4 + j] = hi0[j]; }
        bf16x4 lo1 = *(const bf16x4*)(&sr[base + off2]);
        bf16x8 b1;
        #pragma unroll
        for (int j = 0; j < 4; ++j) { b1[j] = lo1[j]; b1[4 + j] = lo1[j]; }

        #pragma unroll
        for (int mi = 0; mi < 4; ++mi) {
            acc[mi][ni] = __builtin_amdgcn_mfma_f32_16x16x32_bf16(b0, af0[mi], acc[mi][ni], 0, 0, 0);
            acc[mi][ni] = __builtin_amdgcn_mfma_f32_16x16x32_bf16(b1, af1[mi], acc[mi][ni], 0, 0, 0);
        }
    }

    #pragma unroll
    for (int ni = 0; ni < 8; ++ni) {
        int g = wv * 32 + ni * 4 + quad;
        bool ok = (g < 126);
        int ypl = g / 42, xg = g % 42;
        #pragma unroll
        for (int mi = 0; mi < 4; ++mi) {
            f32x4 a = acc[mi][ni];
            float m = fmaxf(fmaxf(a[0], a[1]), fmaxf(a[2], a[3]));
            if (ok) {
                int cout = mi * 16 + ln;
                unsigned short h = f2bf(fmaxf(m + sb[cout], 0.f));
                int py = yp0 + ypl;
                size_t o = (((size_t)img * 44 + py + 1) * 44 + xg + 1) * 64 + cout;
                X1p[o] = (short)h;
            }
        }
    }
}

// ---------------------------------------------------------------------------
// conv2/conv3: MFMA implicit GEMM, pixels = A (M), weights = B (N).
// R9-proven: depth-1 register ping-pong for af (global/L2) and bf (LDS),
// NO barriers in the K-loop, reg-pool epilogue.
// ---------------------------------------------------------------------------
template<int CIN, int COUT, int NWM, int NWN, int MT, int NT, int YPB,
         int WOUT, int HPIN, int WPIN, int HPO, int WPO, int RBI>
__global__ __launch_bounds__(256, 2)
void conv_mfma_kernel(const short* __restrict__ Xp, const short* __restrict__ Wt,
                      const float* __restrict__ bias, short* __restrict__ Yp)
{
    constexpr int ROWS = 2 * YPB + 2, CSTR = CIN + 8;
    constexpr int KC = CIN * 9 / 32, CPT = CIN / 32;
    constexpr int WPAIR = (2 * WOUT + 3) / 4 * 4;
    constexpr int NSLOT = YPB * WPAIR, POOLW = WOUT / 2;
    constexpr int GPR = WPAIR / 4;
    __shared__ short sx[ROWS * WPIN * CSTR];
    __shared__ float sb[COUT];

    const int tid = threadIdx.x;
    const int img = blockIdx.x / RBI, blkrow = blockIdx.x % RBI;
    const int yp0 = blkrow * YPB;
    const int wv = tid >> 6, lane = tid & 63, quad = lane >> 4, ln = lane & 15;
    const int msup = (NWM == 1) ? 0 : (wv >> 1);
    const int nsup = (NWM == 1) ? wv : (wv & 1);

    const short* xsrc = Xp + ((size_t)img * HPIN + 2 * yp0) * (WPIN * CIN);
    for (int i = tid; i < ROWS * WPIN * (CIN / 8); i += 256) {
        int g = i % (CIN / 8), pc = i / (CIN / 8);
        uint4 v = *(const uint4*)(xsrc + (size_t)pc * CIN + g * 8);
        *(uint4*)(&sx[pc * CSTR + g * 8]) = v;
    }
    for (int i = tid; i < COUT; i += 256) sb[i] = bias[i];

    int pbase[NT];
    #pragma unroll
    for (int ni = 0; ni < NT; ++ni) {
        int q = nsup * (NT * 16) + ni * 16 + ln;
        int qc = (q < NSLOT) ? q : (NSLOT - 1);
        int ypl = qc / WPAIR, rem = qc % WPAIR;
        int x = rem >> 1; if (x > WOUT - 1) x = WOUT - 1;
        int dy = rem & 1;
        pbase[ni] = (((2 * ypl + dy) * WPIN + x) * CSTR + quad * 8) * 2;
    }

    f32x4 acc[MT][NT];
    #pragma unroll
    for (int mi = 0; mi < MT; ++mi)
        #pragma unroll
        for (int ni = 0; ni < NT; ++ni) acc[mi][ni] = (f32x4)0.f;

    auto loadAF = [&](bf16x8* dst, int kc) {
        #pragma unroll
        for (int mi = 0; mi < MT; ++mi)
            dst[mi] = *(const bf16x8*)(Wt + ((size_t)kc * COUT + msup * 64 + mi * 16 + ln) * 40 + quad * 8);
    };
    auto loadBF = [&](bf16x8* dst, int kc) {
        const int tap = kc / CPT, cb = (kc % CPT) * 32;
        const int ky = tap / 3, kx = tap % 3;
        const int koff = ((ky * WPIN + kx) * CSTR + cb) * 2;
        #pragma unroll
        for (int ni = 0; ni < NT; ++ni)
            dst[ni] = *(const bf16x8*)((const char*)sx + pbase[ni] + koff);
    };

    __syncthreads();   // sx/sb ready — the ONLY barrier

    bf16x8 afA[MT], afB[MT], bfA[NT], bfB[NT];
    loadAF(afA, 0); loadBF(bfA, 0);
    for (int kc = 0; kc < KC; kc += 2) {
        loadAF(afB, kc + 1); loadBF(bfB, kc + 1);
        #pragma unroll
        for (int mi = 0; mi < MT; ++mi)
            #pragma unroll
            for (int ni = 0; ni < NT; ++ni)
                acc[mi][ni] = __builtin_amdgcn_mfma_f32_16x16x32_bf16(bfA[ni], afA[mi], acc[mi][ni], 0, 0, 0);
        if (kc + 2 < KC) { loadAF(afA, kc + 2); loadBF(bfA, kc + 2); }
        #pragma unroll
        for (int mi = 0; mi < MT; ++mi)
            #pragma unroll
            for (int ni = 0; ni < NT; ++ni)
                acc[mi][ni] = __builtin_amdgcn_mfma_f32_16x16x32_bf16(bfB[ni], afB[mi], acc[mi][ni], 0, 0, 0);
    }

    #pragma unroll
    for (int ni = 0; ni < NT; ++ni) {
        int g = nsup * (NT * 4) + ni * 4 + quad;
        int ypl = g / GPR, xg = g % GPR;
        bool ok = (g < NSLOT / 4) && (xg < POOLW);
        #pragma unroll
        for (int mi = 0; mi < MT; ++mi) {
            f32x4 a = acc[mi][ni];
            float m = fmaxf(fmaxf(a[0], a[1]), fmaxf(a[2], a[3]));
            if (ok) {
                int cout = msup * 64 + mi * 16 + ln;
                unsigned short h = f2bf(fmaxf(m + sb[cout], 0.f));
                int py = yp0 + ypl;
                Yp[(((size_t)img * HPO + py + 1) * WPO + xg + 1) * COUT + cout] = (short)h;
            }
        }
    }
}

// ---------------------------------------------------------------------------
// conv4: image in LDS (CSTR=136), weight frags from global, R9-proven depth-1
// ping-pong, no K-loop barriers, reg-pool epilogue -> f4 NHWC f32 (400,25,512).
// ---------------------------------------------------------------------------
__global__ __launch_bounds__(256, 2)
void conv4_mfma_kernel(const short* __restrict__ X3p, const short* __restrict__ W4t,
                       const float* __restrict__ bias, float* __restrict__ f4)
{
    constexpr int CSTR = 136;
    __shared__ short sx[144 * CSTR];     // 39,168 B
    __shared__ float sb[128];

    const int tid = threadIdx.x;
    const int img = blockIdx.x >> 2, mb = blockIdx.x & 3;
    const int wv = tid >> 6, lane = tid & 63, quad = lane >> 4, ln = lane & 15;
    const int msup = wv >> 1, nsup = wv & 1;

    const short* xsrc = X3p + (size_t)img * (144 * 128);
    for (int i = tid; i < 144 * 16; i += 256) {
        int pc = i >> 4, g = i & 15;
        uint4 v = *(const uint4*)(xsrc + pc * 128 + g * 8);
        *(uint4*)(&sx[pc * CSTR + g * 8]) = v;
    }
    for (int i = tid; i < 128; i += 256) sb[i] = bias[mb * 128 + i];

    int pbase[4];
    #pragma unroll
    for (int ni = 0; ni < 4; ++ni) {
        int q = nsup * 64 + ni * 16 + ln;
        int pc = (q < 100) ? q : 99;
        int yp = pc / 20, rem = pc % 20;
        int y = 2 * yp + (rem & 1), x = rem >> 1;
        pbase[ni] = ((y * 12 + x) * CSTR + quad * 8) * 2;
    }

    f32x4 acc[4][4];
    #pragma unroll
    for (int mi = 0; mi < 4; ++mi)
        #pragma unroll
        for (int ni = 0; ni < 4; ++ni) acc[mi][ni] = (f32x4)0.f;

    auto loadAF = [&](bf16x8* dst, int kc) {
        #pragma unroll
        for (int mi = 0; mi < 4; ++mi)
            dst[mi] = *(const bf16x8*)(W4t + ((size_t)kc * 512 + mb * 128 + msup * 64 + mi * 16 + ln) * 40 + quad * 8);
    };
    auto loadBF = [&](bf16x8* dst, int kc) {
        const int tap = kc >> 2, cb = (kc & 3) * 32;
        const int ky = tap / 3, kx = tap % 3;
        const int koff = ((ky * 12 + kx) * CSTR + cb) * 2;
        #pragma unroll
        for (int ni = 0; ni < 4; ++ni)
            dst[ni] = *(const bf16x8*)((const char*)sx + pbase[ni] + koff);
    };

    __syncthreads();   // sx/sb ready — the ONLY barrier

    bf16x8 afA[4], afB[4], bfA[4], bfB[4];
    loadAF(afA, 0); loadBF(bfA, 0);
    for (int kc = 0; kc < 36; kc += 2) {
        loadAF(afB, kc + 1); loadBF(bfB, kc + 1);
        #pragma unroll
        for (int mi = 0; mi < 4; ++mi)
            #pragma unroll
            for (int ni = 0; ni < 4; ++ni)
                acc[mi][ni] = __builtin_amdgcn_mfma_f32_16x16x32_bf16(bfA[ni], afA[mi], acc[mi][ni], 0, 0, 0);
        if (kc + 2 < 36) { loadAF(afA, kc + 2); loadBF(bfA, kc + 2); }
        #pragma unroll
        for (int mi = 0; mi < 4; ++mi)
            #pragma unroll
            for (int ni = 0; ni < 4; ++ni)
                acc[mi][ni] = __builtin_amdgcn_mfma_f32_16x16x32_bf16(bfB[ni], afB[mi], acc[mi][ni], 0, 0, 0);
    }

    #pragma unroll
    for (int ni = 0; ni < 4; ++ni) {
        int g = nsup * 16 + ni * 4 + quad;
        bool ok = (g < 25);
        #pragma unroll
        for (int mi = 0; mi < 4; ++mi) {
            f32x4 a = acc[mi][ni];
            float m = fmaxf(fmaxf(a[0], a[1]), fmaxf(a[2], a[3]));
            if (ok) {
                int cl = msup * 64 + mi * 16 + ln;
                f4[((size_t)img * 25 + g) * 512 + mb * 128 + cl] = fmaxf(m + sb[cl], 0.f);
            }
        }
    }
}

// ---------------------------------------------------------------------------
// heads (f4 NHWC f32 (400,25,512) -> g, proto, predict, cls)
// ---------------------------------------------------------------------------
__global__ __launch_bounds__(256)
void gap_kernel(const float* __restrict__ f4, float* __restrict__ g)
{
    const int img = blockIdx.x;
    for (int c = threadIdx.x; c < 512; c += 256) {
        float s = 0.f;
        #pragma unroll
        for (int p = 0; p < 25; ++p)
            s += f4[((size_t)img * 25 + p) * 512 + c];
        g[(size_t)img * 512 + c] = s * (1.f / 25.f);
    }
}

__global__ __launch_bounds__(256)
void proto_kernel(const float* __restrict__ g, const float* __restrict__ ytrain,
                  float* __restrict__ proto)
{
    const int b = blockIdx.x / 5, k = blockIdx.x % 5;
    __shared__ float sp[512];
    __shared__ float red[256];

    float yv[25];
    float cnt = 0.f;
    for (int n = 0; n < 25; ++n) {
        yv[n] = ytrain[(size_t)(b * 25 + n) * 5 + k];
        cnt += yv[n];
    }
    const float icnt = 1.f / cnt;

    for (int c = threadIdx.x; c < 512; c += 256) {
        float s = 0.f;
        for (int n = 0; n < 25; ++n)
            s += yv[n] * g[((size_t)(b * 25 + n)) * 512 + c];
        sp[c] = s * icnt;
    }
    __syncthreads();

    float ss = 0.f;
    for (int c = threadIdx.x; c < 512; c += 256) ss += sp[c] * sp[c];
    red[threadIdx.x] = ss;
    __syncthreads();
    for (int s = 128; s > 0; s >>= 1) {
        if (threadIdx.x < s) red[threadIdx.x] += red[threadIdx.x + s];
        __syncthreads();
    }
    const float inv = 1.f / fmaxf(sqrtf(red[0]), 1e-12f);
    for (int c = threadIdx.x; c < 512; c += 256)
        proto[((size_t)(b * 5 + k)) * 512 + c] = sp[c] * inv;
}

// predict: coalesced wcT reads. 256 threads = 4 c-chunks x 64 m; LDS reduce.
__global__ __launch_bounds__(256)
void predict_kernel(const float* __restrict__ g, const float* __restrict__ wcT,
                    const float* __restrict__ bc, float* __restrict__ out)
{
    const int q = blockIdx.x;
    __shared__ float fq[512];
    __shared__ float red[256];
    __shared__ float part[4][64];

    const float* gq = g + (size_t)(100 + q) * 512;
    float ss = 0.f;
    for (int c = threadIdx.x; c < 512; c += 256) {
        const float v = gq[c];
        fq[c] = v;
        ss += v * v;
    }
    red[threadIdx.x] = ss;
    __syncthreads();
    for (int s = 128; s > 0; s >>= 1) {
        if (threadIdx.x < s) red[threadIdx.x] += red[threadIdx.x + s];
        __syncthreads();
    }
    const float inv = 1.f / fmaxf(sqrtf(red[0]), 1e-12f);

    const int cp = threadIdx.x >> 6, m = threadIdx.x & 63;
    float s = 0.f;
    const int c0 = cp * 128;
    for (int c = c0; c < c0 + 128; ++c)
        s = fmaf(fq[c], wcT[c * 64 + m], s);
    part[cp][m] = s;
    __syncthreads();
    if (threadIdx.x < 64)
        out[q * 64 + m] = (part[0][m] + part[1][m] + part[2][m] + part[3][m]) * inv + bc[m];
}

__global__ __launch_bounds__(256)
void cls_kernel(const float* __restrict__ f4, const float* __restrict__ proto,
                float* __restrict__ outc)
{
    __shared__ float sf[25 * 516];      // +4 pad kills 512-stride bank conflicts
    __shared__ float spr[5 * 516];
    __shared__ float pinv[25];
    const int q = blockIdx.x, b = q / 75;
    const float* f = f4 + (size_t)(100 + q) * (25 * 512);
    for (int i = threadIdx.x; i < 3200; i += 256) {
        int row = i >> 7, col = i & 127;
        *(float4*)(&sf[row * 516 + col * 4]) = *(const float4*)(f + row * 512 + col * 4);
    }
    const float* pb = proto + (size_t)b * 5 * 512;
    for (int i = threadIdx.x; i < 640; i += 256) {
        int row = i >> 7, col = i & 127;
        *(float4*)(&spr[row * 516 + col * 4]) = *(const float4*)(pb + row * 512 + col * 4);
    }
    __syncthreads();

    // hoist per-pixel norms (25 of them) out of the 125-dot loop
    if (threadIdx.x < 25) {
        const float* fp = &sf[threadIdx.x * 516];
        float ss = 0.f;
        for (int c = 0; c < 512; c += 4) {
            float4 v = *(const float4*)(fp + c);
            ss += v.x * v.x + v.y * v.y + v.z * v.z + v.w * v.w;
        }
        pinv[threadIdx.x] = 1.f / fmaxf(sqrtf(ss), 1e-12f);
    }
    __syncthreads();

    for (int it = threadIdx.x; it < 125; it += 256) {
        int i = it / 25, p = it % 25;
        const float* fp = &sf[p * 516];
        const float* pr = &spr[i * 516];
        float dot = 0.f;
        for (int c = 0; c < 512; c += 4) {
            float4 v = *(const float4*)(fp + c);
            float4 w = *(const float4*)(pr + c);
            dot += v.x * w.x + v.y * w.y + v.z * w.z + v.w * w.w;
        }
        outc[(size_t)q * 125 + it] = dot * pinv[p];
    }
}

// ---------------------------------------------------------------------------
extern "C" void kernel_launch(void* const* d_in, const int* in_sizes, int n_in,
                              void* d_out, int out_size, void* d_ws, size_t ws_size,
                              hipStream_t stream)
{
    (void)in_sizes; (void)n_in; (void)out_size; (void)ws_size;
    const float* xtrain = (const float*)d_in[0];
    const float* xtest  = (const float*)d_in[1];
    const float* ytrain = (const float*)d_in[2];
    const float* w1 = (const float*)d_in[4];
    const float* b1 = (const float*)d_in[5];
    const float* w2 = (const float*)d_in[6];
    const float* b2 = (const float*)d_in[7];
    const float* w3 = (const float*)d_in[8];
    const float* b3 = (const float*)d_in[9];
    const float* w4 = (const float*)d_in[10];
    const float* b4 = (const float*)d_in[11];
    const float* wc = (const float*)d_in[12];
    const float* bc = (const float*)d_in[13];

    char* ws = (char*)d_ws;
    short* X1p = (short*)(ws + OFF_X1P);
    short* X2p = (short*)(ws + OFF_X2P);
    short* X3p = (short*)(ws + OFF_X3P);
    short* W1t = (short*)(ws + OFF_W1T);
    short* W2t = (short*)(ws + OFF_W2T);
    short* W3t = (short*)(ws + OFF_W3T);
    short* W4t = (short*)(ws + OFF_W4T);
    float* wcT = (float*)(ws + OFF_WCT);
    float* f4    = (float*)(ws + OFF_F4);
    float* g     = (float*)(ws + OFF_G);
    float* proto = (float*)(ws + OFF_PROTO);
    float* out = (float*)d_out;

    // setup: pad rings (1 launch) + weight transforms incl. wc transpose (1 launch)
    border_zero_all_kernel<<<1200, 256, 0, stream>>>(X1p, X2p, X3p);
    wt_all_kernel<<<2884, 256, 0, stream>>>(w1, w2, w3, w4, wc,
                                            W1t, W2t, W3t, W4t, wcT);

    // backbone
    conv1_mfma_kernel<<<400 * 14, 256, 0, stream>>>(xtrain, xtest, W1t, b1, X1p);
    //                CIN COUT NWM NWN MT NT YPB WOUT HPIN WPIN HPO WPO RBI
    conv_mfma_kernel< 64,  64,  1,  4, 4, 4,  3,  42,  44,  44, 23, 23,  7>
        <<<400 * 7, 256, 0, stream>>>(X1p, W2t, b2, X2p);
    conv_mfma_kernel< 64, 128,  2,  2, 4, 7,  5,  21,  23,  23, 12, 12,  2>
        <<<400 * 2, 256, 0, stream>>>(X2p, W3t, b3, X3p);
    conv4_mfma_kernel<<<400 * 4, 256, 0, stream>>>(X3p, W4t, b4, f4);

    // heads
    gap_kernel<<<400, 256, 0, stream>>>(f4, g);
    proto_kernel<<<20, 256, 0, stream>>>(g, ytrain, proto);
    predict_kernel<<<300, 256, 0, stream>>>(g, wcT, bc, out);
    cls_kernel<<<300, 256, 0, stream>>>(f4, proto, out + 19200);
}